// Round 1
// baseline (76.152 us; speedup 1.0000x reference)
//
#include <hip/hip_runtime.h>

#define D 128
#define NCLS 3

// ws layout (floats): [0 .. 383] per-class sums (3 x 128), [384..386] counts (as uint bits)

__global__ __launch_bounds__(256) void class_sum_kernel(
    const float* __restrict__ feat, const int* __restrict__ labels,
    float* __restrict__ sums, unsigned int* __restrict__ counts, int N)
{
    __shared__ float s_sum[NCLS * D];
    __shared__ unsigned int s_cnt[NCLS];
    const int t = threadIdx.x;

    for (int i = t; i < NCLS * D; i += 256) s_sum[i] = 0.0f;
    if (t < NCLS) s_cnt[t] = 0u;
    __syncthreads();

    const int col4 = t & 31;   // which float4 (of 32) within the 128-wide row
    const int rsub = t >> 5;   // 0..7 : row slot within the block's 8-row stripe
    const float4* __restrict__ f4 = (const float4*)feat;

    float4 a0 = make_float4(0.f, 0.f, 0.f, 0.f);
    float4 a1 = make_float4(0.f, 0.f, 0.f, 0.f);
    float4 a2 = make_float4(0.f, 0.f, 0.f, 0.f);
    unsigned int c0 = 0u, c1 = 0u, c2 = 0u;

    for (long long row = (long long)blockIdx.x * 8 + rsub; row < N;
         row += (long long)gridDim.x * 8) {
        const int lab = labels[row];
        const float4 v = f4[row * 32 + col4];
        const float m0 = (lab == 0) ? 1.0f : 0.0f;
        const float m1 = (lab == 1) ? 1.0f : 0.0f;
        const float m2 = (lab == 2) ? 1.0f : 0.0f;
        a0.x = fmaf(v.x, m0, a0.x); a0.y = fmaf(v.y, m0, a0.y);
        a0.z = fmaf(v.z, m0, a0.z); a0.w = fmaf(v.w, m0, a0.w);
        a1.x = fmaf(v.x, m1, a1.x); a1.y = fmaf(v.y, m1, a1.y);
        a1.z = fmaf(v.z, m1, a1.z); a1.w = fmaf(v.w, m1, a1.w);
        a2.x = fmaf(v.x, m2, a2.x); a2.y = fmaf(v.y, m2, a2.y);
        a2.z = fmaf(v.z, m2, a2.z); a2.w = fmaf(v.w, m2, a2.w);
        c0 += (lab == 0); c1 += (lab == 1); c2 += (lab == 2);
    }

    // block-level reduce into LDS
    const int base = col4 * 4;
    atomicAdd(&s_sum[0 * D + base + 0], a0.x);
    atomicAdd(&s_sum[0 * D + base + 1], a0.y);
    atomicAdd(&s_sum[0 * D + base + 2], a0.z);
    atomicAdd(&s_sum[0 * D + base + 3], a0.w);
    atomicAdd(&s_sum[1 * D + base + 0], a1.x);
    atomicAdd(&s_sum[1 * D + base + 1], a1.y);
    atomicAdd(&s_sum[1 * D + base + 2], a1.z);
    atomicAdd(&s_sum[1 * D + base + 3], a1.w);
    atomicAdd(&s_sum[2 * D + base + 0], a2.x);
    atomicAdd(&s_sum[2 * D + base + 1], a2.y);
    atomicAdd(&s_sum[2 * D + base + 2], a2.z);
    atomicAdd(&s_sum[2 * D + base + 3], a2.w);
    if (col4 == 0) {  // one counting thread per row slot (8 per block)
        atomicAdd(&s_cnt[0], c0);
        atomicAdd(&s_cnt[1], c1);
        atomicAdd(&s_cnt[2], c2);
    }
    __syncthreads();

    // one global atomic per element per block
    for (int i = t; i < NCLS * D; i += 256) atomicAdd(&sums[i], s_sum[i]);
    if (t < NCLS) atomicAdd(&counts[t], s_cnt[t]);
}

__global__ __launch_bounds__(128) void finalize_kernel(
    const float* __restrict__ sums, const unsigned int* __restrict__ counts,
    float* __restrict__ out, int tail)
{
    __shared__ float s_red[NCLS][2];
    const int t = threadIdx.x;           // 128 threads, one per column
    const int lane = t & 63;
    const int wv = t >> 6;

    float center[NCLS];
    #pragma unroll
    for (int k = 0; k < NCLS; k++) {
        const float cnt = (float)counts[k];
        center[k] = sums[k * D + t] / cnt;
    }

    #pragma unroll
    for (int k = 0; k < NCLS; k++) {
        float sq = center[k] * center[k];
        #pragma unroll
        for (int off = 32; off > 0; off >>= 1) sq += __shfl_down(sq, off, 64);
        if (lane == 0) s_red[k][wv] = sq;
    }
    __syncthreads();

    #pragma unroll
    for (int k = 0; k < NCLS; k++) {
        const float norm = sqrtf(s_red[k][0] + s_red[k][1]);
        out[k * D + t] = center[k] / fmaxf(norm, 1e-12f);
    }
    // second tuple output: target = arange(NUM_CLASSES), stored as output dtype
    if (t < tail) out[NCLS * D + t] = (float)t;
}

extern "C" void kernel_launch(void* const* d_in, const int* in_sizes, int n_in,
                              void* d_out, int out_size, void* d_ws, size_t ws_size,
                              hipStream_t stream) {
    const float* feat = (const float*)d_in[0];
    const int* labels = (const int*)d_in[1];
    const int N = in_sizes[1];

    float* sums = (float*)d_ws;
    unsigned int* counts = (unsigned int*)((float*)d_ws + NCLS * D);

    // zero the accumulator workspace every call (harness poisons ws once, never restores)
    hipMemsetAsync(d_ws, 0, (NCLS * D + NCLS) * sizeof(float), stream);

    const int grid = 1024;
    class_sum_kernel<<<grid, 256, 0, stream>>>(feat, labels, sums, counts, N);

    int tail = out_size - NCLS * D;
    if (tail < 0) tail = 0;
    if (tail > D) tail = D;
    finalize_kernel<<<1, 128, 0, stream>>>(sums, counts, (float*)d_out, tail);
}